// Round 6
// baseline (2036.490 us; speedup 1.0000x reference)
//
#include <hip/hip_runtime.h>

namespace {
constexpr int NB = 1024, NT = 1024, NH = 128;
constexpr float L2E = 1.4426950408889634f;

typedef __bf16 bf16x8 __attribute__((ext_vector_type(8)));
typedef float  f32x4  __attribute__((ext_vector_type(4)));
typedef int    i32x4  __attribute__((ext_vector_type(4)));
union FRAG { i32x4 i; bf16x8 b; };

__device__ __forceinline__ unsigned short bfb(float f) {   // HW RNE f32->bf16
  union { __bf16 h; unsigned short u; } c; c.h = (__bf16)f; return c.u;
}
__device__ __forceinline__ unsigned pkbf(float a, float b) {
  return (unsigned)bfb(a) | ((unsigned)bfb(b) << 16);
}
__device__ __forceinline__ unsigned long long pk4(const f32x4 v) {
  return (unsigned long long)pkbf(v[0], v[1]) |
         ((unsigned long long)pkbf(v[2], v[3]) << 32);
}
__device__ __forceinline__ float ex2(float x) { return __builtin_amdgcn_exp2f(x); }
__device__ __forceinline__ float rcp_(float x) { return __builtin_amdgcn_rcpf(x); }

// 8 consecutive floats -> bf16 fragment (k = 32s + 8lg + j map, verified r0/r1)
__device__ __forceinline__ FRAG pk8(const float* pp, float sc) {
  FRAG f;
  #pragma unroll
  for (int j = 0; j < 4; ++j)
    f.i[j] = (int)pkbf(pp[2 * j] * sc, pp[2 * j + 1] * sc);
  return f;
}
} // namespace

#define MFMA(a, b, c) __builtin_amdgcn_mfma_f32_16x16x32_bf16(a, b, c, 0, 0, 0)
// LDS-only barrier: never drains vmcnt (global stores / x-prefetch stay in flight)
#define BAR() do { \
  asm volatile("s_waitcnt lgkmcnt(0)" ::: "memory"); \
  __builtin_amdgcn_s_barrier(); \
} while (0)

// One block = 16 batch rows, 1024 threads (16 waves), single dispatch.
// Waves 0-7  (gate): GRU-D recurrence step t (operand-swapped: weights=A,
//                    state=B, D=[unit,batch]; 8B LDS writes; 5-trans tail).
// Waves 8-11: head-L1 is shared by all head waves; plus x stagers (sid<208);
//             wave 8 = L2-pred(t-2), wave 9 = L2-unc(t-2).
// Waves 12-15: head-L1 + u1 tiles + x_hat lanes (lanes<24).
// ONE LDS-only barrier per step; every LDS buffer double-buffered by parity:
//   gates: R gin[p], hdL[p], xw[q](dt)   W hnb[p], hdL[q]
//   L1(t-1): R hnb[q]                    W y1s[q], u1s[q]
//   L2(t-2): R y1s[p], u1s[p]            W out (global, in flight)
//   xhat(t+1): R xw[q]                   W gin[q]
//   stager: W xw[p] = x[t+2]
__global__ __launch_bounds__(1024)
void grud_fused(const float* __restrict__ x,   const float* __restrict__ x_mean,
                const float* __restrict__ dxw, const float* __restrict__ dxb,
                const float* __restrict__ dhw, const float* __restrict__ dhb,
                const float* __restrict__ w_ih, const float* __restrict__ w_hh,
                const float* __restrict__ b_ih, const float* __restrict__ b_hh,
                const float* __restrict__ w1,  const float* __restrict__ b1,
                const float* __restrict__ w2,  const float* __restrict__ b2,
                const float* __restrict__ wu1, const float* __restrict__ bu1,
                const float* __restrict__ wu2, const float* __restrict__ bu2,
                float* __restrict__ out)
{
  __shared__ __align__(16) float          xw[2][16][17];   // x rows, 17-pad
  __shared__ __align__(16) unsigned short gin[2][16][40];  // interleaved x̂/m + bias
  __shared__ __align__(16) unsigned short hdL[2][2048];    // decayed h [b][u] swz
  __shared__ __align__(16) unsigned short hnb[2][2048];    // new h     [b][u] swz
  __shared__ __align__(16) unsigned short y1s[2][2048];    // relu(h@w1) [b][u] swz
  __shared__ __align__(16) unsigned short u1s[2][1024];    // relu(h@wu1) [b][u] swz

  const int tid = threadIdx.x, lane = tid & 63, wv = tid >> 6;
  const int lr = lane & 15, lg = lane >> 4;
  const int b0 = blockIdx.x * 16;
  const bool isGate = wv < 8;
  const int hw = wv & 7;

  // ---------------- role-shared weight fragments ----------------
  FRAG wf[15];
  f32x4 dhwV = {0.f,0.f,0.f,0.f}, dhbV = {0.f,0.f,0.f,0.f}, bhnV = {0.f,0.f,0.f,0.f};
  float b1l = 0.f, bu1l = 0.f, b2l = 0.f, bu2l = 0.f;

  if (isGate) {
    const int uidx = wv * 16 + lr;        // weight row (A operand)
    const int uu0  = wv * 16 + 4 * lg;    // first owned unit (D rows)
    #pragma unroll
    for (int g = 0; g < 3; ++g) {
      const float sc = (g < 2) ? -L2E : 2.f * L2E;
      const int grow = g * 128 + uidx;
      const float* wrow = w_hh + (size_t)grow * NH;
      #pragma unroll
      for (int s = 0; s < 4; ++s) wf[g * 4 + s] = pk8(wrow + 32 * s + 8 * lg, sc);
      FRAG f; f.i = i32x4{0, 0, 0, 0};
      if (lg < 2) {
        unsigned e[8];
        #pragma unroll
        for (int j = 0; j < 8; ++j) {
          const int c = 8 * lg + j; float v = 0.f;
          if (c < 12) {
            const int ch = c >> 1;
            v = ((c & 1) ? w_ih[(size_t)grow * 12 + 6 + ch]
                         : w_ih[(size_t)grow * 12 + ch]) * sc;
          } else if (c == 12) {
            v = ((g < 2) ? (b_ih[grow] + b_hh[grow]) : b_ih[grow]) * sc;
          }
          e[j] = bfb(v);
        }
        f.i[0] = (int)(e[0] | (e[1] << 16)); f.i[1] = (int)(e[2] | (e[3] << 16));
        f.i[2] = (int)(e[4] | (e[5] << 16)); f.i[3] = (int)(e[6] | (e[7] << 16));
      }
      wf[12 + g] = f;
    }
    #pragma unroll
    for (int r = 0; r < 4; ++r) {
      dhwV[r] = -L2E * dhw[uu0 + r];
      dhbV[r] = -L2E * dhb[uu0 + r];
      bhnV[r] = b_hh[256 + uu0 + r] * (2.f * L2E);
    }
  } else {
    const int ut = (wv - 8) & 3;
    #pragma unroll
    for (int s = 0; s < 4; ++s) {
      wf[s]     = pk8(w1  + (size_t)(hw * 16 + lr) * 128 + 32 * s + 8 * lg, 1.f);
      wf[4 + s] = pk8(wu1 + (size_t)(ut * 16 + lr) * 128 + 32 * s + 8 * lg, 1.f);
      if (lr < 6) wf[8 + s] = pk8(w2 + (size_t)lr * 128 + 32 * s + 8 * lg, 1.f);
      else        wf[8 + s].i = i32x4{0, 0, 0, 0};
    }
    #pragma unroll
    for (int s = 0; s < 2; ++s) {
      if (lr < 6) wf[12 + s] = pk8(wu2 + (size_t)lr * 64 + 32 * s + 8 * lg, 1.f);
      else        wf[12 + s].i = i32x4{0, 0, 0, 0};
    }
    wf[14].i = i32x4{0, 0, 0, 0};
    b1l = b1[hw * 16 + lr]; bu1l = bu1[ut * 16 + lr];
    b2l = (lr < 6) ? b2[lr] : 0.f; bu2l = (lr < 6) ? bu2[lr] : 0.f;
  }

  // ---------------- x̂ lanes: waves 12-15, lanes < 24 ----------------
  const bool xl = (wv >= 12) && (lane < 24);
  const int xi = (wv - 12) * 24 + lane;
  int xrow = 0, xch = 0;
  float dxwS = 0.f, dxbS = 0.f, xm_l = 0.f, run = 0.f, xlast = 0.f;
  if (xl) {
    xrow = xi / 6; xch = xi - 6 * xrow;
    dxwS = -L2E * dxw[xch]; dxbS = -L2E * dxb[xch]; xm_l = x_mean[xch];
  }

  // ---------------- stagers: waves 8-11, sid < 208 ----------------
  const int sid = tid - 512;
  const bool sl = (sid >= 0) && (sid < 208);
  int rrow = 0, rcc = 0;
  if (sl) { rrow = sid / 13; rcc = sid - 13 * rrow; }
  const float* xbase = x + (size_t)(b0 + rrow) * (NT * 13) + rcc;

  // ---------------- constant LDS byte offsets ----------------
  const int wOff = lr * 256 + (((2 * wv + (lg >> 1)) ^ (lr & 7)) << 4) + (lg & 1) * 8;
  int rOff[4], rOff64[2];
  #pragma unroll
  for (int s = 0; s < 4; ++s) rOff[s] = lr * 256 + (((4 * s + lg) ^ (lr & 7)) << 4);
  #pragma unroll
  for (int s = 0; s < 2; ++s) rOff64[s] = lr * 128 + (((4 * s + lg) ^ (lr & 7)) << 4);
  int yWo[4], uWo[4];
  {
    const int cy = hw * 16 + lr, cu = ((wv - 8) & 3) * 16 + lr;
    #pragma unroll
    for (int r = 0; r < 4; ++r) {
      const int m = 4 * lg + r;
      yWo[r] = m * 256 + (((cy >> 3) ^ (m & 7)) << 4) + (cy & 7) * 2;
      uWo[r] = m * 128 + (((cu >> 3) ^ (m & 7)) << 4) + (cu & 7) * 2;
    }
  }

  // ---------------- prologue ----------------
  ((unsigned*)hdL)[tid] = 0u;     // zero hdL[0] (4KB = 1024 u32)
  if (tid < 2 * 16 * 28) {        // gin cols 12..39 (bias col 12 = 1.0)
    const int buf = tid / 448, rem = tid - 448 * buf;
    const int row = rem / 28, c = 12 + rem - 28 * (rem / 28);
    gin[buf][row][c] = (c == 12) ? (unsigned short)0x3F80 : (unsigned short)0;
  }
  if (sl) { xw[0][rrow][rcc] = xbase[0]; xw[1][rrow][rcc] = xbase[13]; }
  __syncthreads();
  if (xl) {                       // x̂ for t = 0
    const float xv = xw[0][xrow][xch], mt = xw[0][xrow][6 + xch];
    const float dtv = xw[0][xrow][12];
    const bool obs = mt > 0.5f;
    run = obs ? 0.f : run + dtv;
    const float gx = ex2(fminf(run * dxwS + dxbS, 0.f));
    xlast = obs ? xv : xlast;
    const float xh = mt * xv + (1.f - mt) * (gx * xlast + (1.f - gx) * xm_l);
    ((unsigned*)&gin[0][xrow][0])[xch] = pkbf(xh, mt);
  }
  float xr2 = 0.f;
  if (sl) xr2 = xbase[26];        // x[2]
  BAR();

  f32x4 hd = {0.f,0.f,0.f,0.f}, hn = {0.f,0.f,0.f,0.f};
  const f32x4 z4 = {0.f,0.f,0.f,0.f};

  // ---------------- main loop: gates(t) | L1(t-1) | L2(t-2) ----------------
  #pragma unroll 1
  for (int st = 0; st < NT + 2; ++st) {
    const int p = st & 1, q = p ^ 1;

    if (isGate) {
      if (st < NT) {
        // gamma for t+1 hoisted (dt_{t+1} already staged; overlaps MFMAs)
        const float dtn = xw[q][lr][12];
        f32x4 gmn;
        #pragma unroll
        for (int r = 0; r < 4; ++r)
          gmn[r] = ex2(fminf(dtn * dhwV[r] + dhbV[r], 0.f));

        FRAG ag; ag.i = *(const i32x4*)&gin[p][lr][8 * lg];
        FRAG ah[4];
        #pragma unroll
        for (int s = 0; s < 4; ++s)
          ah[s].i = *(const i32x4*)((const char*)hdL + p * 4096 + rOff[s]);

        f32x4 accr = MFMA(wf[12].b, ag.b, z4);
        f32x4 accz = MFMA(wf[13].b, ag.b, z4);
        f32x4 ani  = MFMA(wf[14].b, ag.b, z4);
        f32x4 anh  = z4;
        #pragma unroll
        for (int s = 0; s < 4; ++s) {
          accr = MFMA(wf[s].b,     ah[s].b, accr);
          accz = MFMA(wf[4 + s].b, ah[s].b, accz);
          anh  = MFMA(wf[8 + s].b, ah[s].b, anh);
        }

        // 5-trans tail: hn = [(En-1)Ez + hd(En+1)] / [(En+1)(1+Ez)]
        f32x4 hbv = anh + bhnV;
        #pragma unroll
        for (int r = 0; r < 4; ++r) {
          const float Er = ex2(accr[r]);
          const float rr = rcp_(1.f + Er);
          const float na = __builtin_fmaf(rr, hbv[r], ani[r]);
          const float En = ex2(na);
          const float Ez = ex2(accz[r]);
          const float em1 = En - 1.f, ep1 = En + 1.f;
          const float num = __builtin_fmaf(hd[r], ep1, em1 * Ez);
          const float den = ep1 * (1.f + Ez);
          hn[r] = num * rcp_(den);
        }

        *(unsigned long long*)((char*)hnb + p * 4096 + wOff) = pk4(hn);
        #pragma unroll
        for (int r = 0; r < 4; ++r) hd[r] = gmn[r] * hn[r];
        *(unsigned long long*)((char*)hdL + q * 4096 + wOff) = pk4(hd);
      }
    } else {
      if (st >= 1 && st <= NT) {           // L1 for step t' = st-1 (parity q)
        FRAG A[4];
        #pragma unroll
        for (int s = 0; s < 4; ++s)
          A[s].i = *(const i32x4*)((const char*)hnb + q * 4096 + rOff[s]);
        f32x4 aa = z4;
        #pragma unroll
        for (int s = 0; s < 4; ++s) aa = MFMA(A[s].b, wf[s].b, aa);
        #pragma unroll
        for (int r = 0; r < 4; ++r)
          *(unsigned short*)((char*)y1s + q * 4096 + yWo[r]) =
              bfb(fmaxf(aa[r] + b1l, 0.f));
        if (wv >= 12) {
          f32x4 au = z4;
          #pragma unroll
          for (int s = 0; s < 4; ++s) au = MFMA(A[s].b, wf[4 + s].b, au);
          #pragma unroll
          for (int r = 0; r < 4; ++r)
            *(unsigned short*)((char*)u1s + q * 2048 + uWo[r]) =
                bfb(fmaxf(au[r] + bu1l, 0.f));
        }
      }
      if (st >= 2) {                       // L2 for step t'' = st-2 (parity p)
        const int t2 = st - 2;
        if (wv == 8) {
          FRAG Y[4];
          #pragma unroll
          for (int s = 0; s < 4; ++s)
            Y[s].i = *(const i32x4*)((const char*)y1s + p * 4096 + rOff[s]);
          f32x4 ap = z4;
          #pragma unroll
          for (int s = 0; s < 4; ++s) ap = MFMA(Y[s].b, wf[8 + s].b, ap);
          if (lr < 6) {
            #pragma unroll
            for (int r = 0; r < 4; ++r)
              out[((size_t)(b0 + 4 * lg + r) * NT + t2) * 6 + lr] = ap[r] + b2l;
          }
        } else if (wv == 9) {
          FRAG U[2];
          #pragma unroll
          for (int s = 0; s < 2; ++s)
            U[s].i = *(const i32x4*)((const char*)u1s + p * 2048 + rOff64[s]);
          f32x4 aq = z4;
          #pragma unroll
          for (int s = 0; s < 2; ++s) aq = MFMA(U[s].b, wf[12 + s].b, aq);
          if (lr < 6) {
            #pragma unroll
            for (int r = 0; r < 4; ++r) {
              const float xa = aq[r] + bu2l;
              const float sp = fmaxf(xa, 0.f) + 0.6931471805599453f *
                  __builtin_amdgcn_logf(1.f + ex2(-fabsf(xa) * L2E));
              out[(size_t)NB * NT * 6 +
                  ((size_t)(b0 + 4 * lg + r) * NT + t2) * 6 + lr] = sp;
            }
          }
        }
      }
      if (xl && st + 1 < NT) {             // x̂ for t+1 (reads xw[q] -> gin[q])
        const float xv = xw[q][xrow][xch], mt = xw[q][xrow][6 + xch];
        const float dtv = xw[q][xrow][12];
        const bool obs = mt > 0.5f;
        run = obs ? 0.f : run + dtv;
        const float gx = ex2(fminf(run * dxwS + dxbS, 0.f));
        xlast = obs ? xv : xlast;
        const float xh = mt * xv + (1.f - mt) * (gx * xlast + (1.f - gx) * xm_l);
        ((unsigned*)&gin[q][xrow][0])[xch] = pkbf(xh, mt);
      }
      if (sl && st + 2 < NT) {             // stage x[t+2] -> xw[p]; prefetch
        xw[p][rrow][rcc] = xr2;
        xr2 = xbase[(size_t)((st + 3 < NT) ? st + 3 : NT - 1) * 13];
      }
    }
    BAR();
  }
}

extern "C" void kernel_launch(void* const* d_in, const int* in_sizes, int n_in,
                              void* d_out, int out_size, void* d_ws, size_t ws_size,
                              hipStream_t stream) {
  (void)in_sizes; (void)n_in; (void)out_size; (void)d_ws; (void)ws_size;
  const float* p[18];
  for (int i = 0; i < 18; ++i) p[i] = (const float*)d_in[i];
  hipLaunchKernelGGL(grud_fused, dim3(64), dim3(1024), 0, stream,
                     p[0], p[1], p[2], p[3], p[4], p[5], p[6], p[7], p[8], p[9],
                     p[10], p[11], p[12], p[13], p[14], p[15], p[16], p[17],
                     (float*)d_out);
}

// Round 7
// 2035.704 us; speedup vs baseline: 1.0004x; 1.0004x over previous
//
#include <hip/hip_runtime.h>

namespace {
constexpr int NB = 1024, NT = 1024, NH = 128;
constexpr float L2E = 1.4426950408889634f;

typedef __bf16 bf16x8 __attribute__((ext_vector_type(8)));
typedef float  f32x4  __attribute__((ext_vector_type(4)));
typedef int    i32x4  __attribute__((ext_vector_type(4)));
union FRAG { i32x4 i; bf16x8 b; };

__device__ __forceinline__ unsigned short bfb(float f) {   // HW RNE f32->bf16
  union { __bf16 h; unsigned short u; } c; c.h = (__bf16)f; return c.u;
}
__device__ __forceinline__ unsigned pkbf(float a, float b) {
  return (unsigned)bfb(a) | ((unsigned)bfb(b) << 16);
}
__device__ __forceinline__ unsigned long long pk4(const f32x4 v) {
  return (unsigned long long)pkbf(v[0], v[1]) |
         ((unsigned long long)pkbf(v[2], v[3]) << 32);
}
__device__ __forceinline__ float ex2(float x) { return __builtin_amdgcn_exp2f(x); }
__device__ __forceinline__ float rcp_(float x) { return __builtin_amdgcn_rcpf(x); }

// 8 consecutive floats -> bf16 fragment (k = 32s + 8lg + j map, verified r0/r1)
__device__ __forceinline__ FRAG pk8(const float* pp, float sc) {
  FRAG f;
  #pragma unroll
  for (int j = 0; j < 4; ++j)
    f.i[j] = (int)pkbf(pp[2 * j] * sc, pp[2 * j + 1] * sc);
  return f;
}
} // namespace

#define MFMA(a, b, c) __builtin_amdgcn_mfma_f32_16x16x32_bf16(a, b, c, 0, 0, 0)
// LDS-only barrier: never drains vmcnt (global stores / x-prefetch stay in flight)
#define BAR() do { \
  asm volatile("s_waitcnt lgkmcnt(0)" ::: "memory"); \
  __builtin_amdgcn_s_barrier(); \
} while (0)

// One block = 16 batch rows, 1024 threads (16 waves), single dispatch.
// Identical structure to round 6 EXCEPT __launch_bounds__(1024, 4):
// min 4 waves/EU -> VGPR cap 128 (was 64 -> scratch spills on the serial
// critical path; fused FETCH_SIZE 29.6MB vs split 14.4MB was the evidence).
// Waves 0-7  (gate): GRU-D recurrence step t (weights=A, state=B,
//                    D=[unit,batch]; 8B LDS writes; 5-trans tail).
// Waves 8-11: stagers (sid<208); wave 8 = L2-pred(t-2), wave 9 = L2-unc(t-2).
// Waves 8-15: head-L1(t-1); waves 12-15 also wu1 tiles + x_hat lanes (<24).
// ONE LDS-only barrier per step; all LDS buffers double-buffered by parity:
//   gates: R gin[p], hdL[p], xw[q](dt)   W hnb[p], hdL[q]
//   L1(t-1): R hnb[q]                    W y1s[q], u1s[q]
//   L2(t-2): R y1s[p], u1s[p]            W out (global, in flight)
//   xhat(t+1): R xw[q]                   W gin[q]
//   stager: W xw[p] = x[t+2]
__global__ __launch_bounds__(1024, 4)
void grud_fused(const float* __restrict__ x,   const float* __restrict__ x_mean,
                const float* __restrict__ dxw, const float* __restrict__ dxb,
                const float* __restrict__ dhw, const float* __restrict__ dhb,
                const float* __restrict__ w_ih, const float* __restrict__ w_hh,
                const float* __restrict__ b_ih, const float* __restrict__ b_hh,
                const float* __restrict__ w1,  const float* __restrict__ b1,
                const float* __restrict__ w2,  const float* __restrict__ b2,
                const float* __restrict__ wu1, const float* __restrict__ bu1,
                const float* __restrict__ wu2, const float* __restrict__ bu2,
                float* __restrict__ out)
{
  __shared__ __align__(16) float          xw[2][16][17];   // x rows, 17-pad
  __shared__ __align__(16) unsigned short gin[2][16][40];  // interleaved x̂/m + bias
  __shared__ __align__(16) unsigned short hdL[2][2048];    // decayed h [b][u] swz
  __shared__ __align__(16) unsigned short hnb[2][2048];    // new h     [b][u] swz
  __shared__ __align__(16) unsigned short y1s[2][2048];    // relu(h@w1) [b][u] swz
  __shared__ __align__(16) unsigned short u1s[2][1024];    // relu(h@wu1) [b][u] swz

  const int tid = threadIdx.x, lane = tid & 63, wv = tid >> 6;
  const int lr = lane & 15, lg = lane >> 4;
  const int b0 = blockIdx.x * 16;
  const bool isGate = wv < 8;
  const int hw = wv & 7;

  // ---------------- role-shared weight fragments ----------------
  FRAG wf[15];
  f32x4 dhwV = {0.f,0.f,0.f,0.f}, dhbV = {0.f,0.f,0.f,0.f}, bhnV = {0.f,0.f,0.f,0.f};
  float b1l = 0.f, bu1l = 0.f, b2l = 0.f, bu2l = 0.f;

  if (isGate) {
    const int uidx = wv * 16 + lr;        // weight row (A operand)
    const int uu0  = wv * 16 + 4 * lg;    // first owned unit (D rows)
    #pragma unroll
    for (int g = 0; g < 3; ++g) {
      const float sc = (g < 2) ? -L2E : 2.f * L2E;
      const int grow = g * 128 + uidx;
      const float* wrow = w_hh + (size_t)grow * NH;
      #pragma unroll
      for (int s = 0; s < 4; ++s) wf[g * 4 + s] = pk8(wrow + 32 * s + 8 * lg, sc);
      FRAG f; f.i = i32x4{0, 0, 0, 0};
      if (lg < 2) {
        unsigned e[8];
        #pragma unroll
        for (int j = 0; j < 8; ++j) {
          const int c = 8 * lg + j; float v = 0.f;
          if (c < 12) {
            const int ch = c >> 1;
            v = ((c & 1) ? w_ih[(size_t)grow * 12 + 6 + ch]
                         : w_ih[(size_t)grow * 12 + ch]) * sc;
          } else if (c == 12) {
            v = ((g < 2) ? (b_ih[grow] + b_hh[grow]) : b_ih[grow]) * sc;
          }
          e[j] = bfb(v);
        }
        f.i[0] = (int)(e[0] | (e[1] << 16)); f.i[1] = (int)(e[2] | (e[3] << 16));
        f.i[2] = (int)(e[4] | (e[5] << 16)); f.i[3] = (int)(e[6] | (e[7] << 16));
      }
      wf[12 + g] = f;
    }
    #pragma unroll
    for (int r = 0; r < 4; ++r) {
      dhwV[r] = -L2E * dhw[uu0 + r];
      dhbV[r] = -L2E * dhb[uu0 + r];
      bhnV[r] = b_hh[256 + uu0 + r] * (2.f * L2E);
    }
  } else {
    const int ut = (wv - 8) & 3;
    #pragma unroll
    for (int s = 0; s < 4; ++s) {
      wf[s]     = pk8(w1  + (size_t)(hw * 16 + lr) * 128 + 32 * s + 8 * lg, 1.f);
      wf[4 + s] = pk8(wu1 + (size_t)(ut * 16 + lr) * 128 + 32 * s + 8 * lg, 1.f);
      if (lr < 6) wf[8 + s] = pk8(w2 + (size_t)lr * 128 + 32 * s + 8 * lg, 1.f);
      else        wf[8 + s].i = i32x4{0, 0, 0, 0};
    }
    #pragma unroll
    for (int s = 0; s < 2; ++s) {
      if (lr < 6) wf[12 + s] = pk8(wu2 + (size_t)lr * 64 + 32 * s + 8 * lg, 1.f);
      else        wf[12 + s].i = i32x4{0, 0, 0, 0};
    }
    wf[14].i = i32x4{0, 0, 0, 0};
    b1l = b1[hw * 16 + lr]; bu1l = bu1[ut * 16 + lr];
    b2l = (lr < 6) ? b2[lr] : 0.f; bu2l = (lr < 6) ? bu2[lr] : 0.f;
  }

  // ---------------- x̂ lanes: waves 12-15, lanes < 24 ----------------
  const bool xl = (wv >= 12) && (lane < 24);
  const int xi = (wv - 12) * 24 + lane;
  int xrow = 0, xch = 0;
  float dxwS = 0.f, dxbS = 0.f, xm_l = 0.f, run = 0.f, xlast = 0.f;
  if (xl) {
    xrow = xi / 6; xch = xi - 6 * xrow;
    dxwS = -L2E * dxw[xch]; dxbS = -L2E * dxb[xch]; xm_l = x_mean[xch];
  }

  // ---------------- stagers: waves 8-11, sid < 208 ----------------
  const int sid = tid - 512;
  const bool sl = (sid >= 0) && (sid < 208);
  int rrow = 0, rcc = 0;
  if (sl) { rrow = sid / 13; rcc = sid - 13 * rrow; }
  const float* xbase = x + (size_t)(b0 + rrow) * (NT * 13) + rcc;

  // ---------------- constant LDS byte offsets ----------------
  const int wOff = lr * 256 + (((2 * wv + (lg >> 1)) ^ (lr & 7)) << 4) + (lg & 1) * 8;
  int rOff[4], rOff64[2];
  #pragma unroll
  for (int s = 0; s < 4; ++s) rOff[s] = lr * 256 + (((4 * s + lg) ^ (lr & 7)) << 4);
  #pragma unroll
  for (int s = 0; s < 2; ++s) rOff64[s] = lr * 128 + (((4 * s + lg) ^ (lr & 7)) << 4);
  int yWo[4], uWo[4];
  {
    const int cy = hw * 16 + lr, cu = ((wv - 8) & 3) * 16 + lr;
    #pragma unroll
    for (int r = 0; r < 4; ++r) {
      const int m = 4 * lg + r;
      yWo[r] = m * 256 + (((cy >> 3) ^ (m & 7)) << 4) + (cy & 7) * 2;
      uWo[r] = m * 128 + (((cu >> 3) ^ (m & 7)) << 4) + (cu & 7) * 2;
    }
  }

  // ---------------- prologue ----------------
  ((unsigned*)hdL)[tid] = 0u;     // zero hdL[0] (4KB = 1024 u32)
  if (tid < 2 * 16 * 28) {        // gin cols 12..39 (bias col 12 = 1.0)
    const int buf = tid / 448, rem = tid - 448 * buf;
    const int row = rem / 28, c = 12 + rem - 28 * (rem / 28);
    gin[buf][row][c] = (c == 12) ? (unsigned short)0x3F80 : (unsigned short)0;
  }
  if (sl) { xw[0][rrow][rcc] = xbase[0]; xw[1][rrow][rcc] = xbase[13]; }
  __syncthreads();
  if (xl) {                       // x̂ for t = 0
    const float xv = xw[0][xrow][xch], mt = xw[0][xrow][6 + xch];
    const float dtv = xw[0][xrow][12];
    const bool obs = mt > 0.5f;
    run = obs ? 0.f : run + dtv;
    const float gx = ex2(fminf(run * dxwS + dxbS, 0.f));
    xlast = obs ? xv : xlast;
    const float xh = mt * xv + (1.f - mt) * (gx * xlast + (1.f - gx) * xm_l);
    ((unsigned*)&gin[0][xrow][0])[xch] = pkbf(xh, mt);
  }
  float xr2 = 0.f;
  if (sl) xr2 = xbase[26];        // x[2]
  BAR();

  f32x4 hd = {0.f,0.f,0.f,0.f}, hn = {0.f,0.f,0.f,0.f};
  const f32x4 z4 = {0.f,0.f,0.f,0.f};

  // ---------------- main loop: gates(t) | L1(t-1) | L2(t-2) ----------------
  #pragma unroll 1
  for (int st = 0; st < NT + 2; ++st) {
    const int p = st & 1, q = p ^ 1;

    if (isGate) {
      if (st < NT) {
        // gamma for t+1 hoisted (dt_{t+1} already staged; overlaps MFMAs)
        const float dtn = xw[q][lr][12];
        f32x4 gmn;
        #pragma unroll
        for (int r = 0; r < 4; ++r)
          gmn[r] = ex2(fminf(dtn * dhwV[r] + dhbV[r], 0.f));

        FRAG ag; ag.i = *(const i32x4*)&gin[p][lr][8 * lg];
        FRAG ah[4];
        #pragma unroll
        for (int s = 0; s < 4; ++s)
          ah[s].i = *(const i32x4*)((const char*)hdL + p * 4096 + rOff[s]);

        f32x4 accr = MFMA(wf[12].b, ag.b, z4);
        f32x4 accz = MFMA(wf[13].b, ag.b, z4);
        f32x4 ani  = MFMA(wf[14].b, ag.b, z4);
        f32x4 anh  = z4;
        #pragma unroll
        for (int s = 0; s < 4; ++s) {
          accr = MFMA(wf[s].b,     ah[s].b, accr);
          accz = MFMA(wf[4 + s].b, ah[s].b, accz);
          anh  = MFMA(wf[8 + s].b, ah[s].b, anh);
        }

        // 5-trans tail: hn = [(En-1)Ez + hd(En+1)] / [(En+1)(1+Ez)]
        f32x4 hbv = anh + bhnV;
        #pragma unroll
        for (int r = 0; r < 4; ++r) {
          const float Er = ex2(accr[r]);
          const float rr = rcp_(1.f + Er);
          const float na = __builtin_fmaf(rr, hbv[r], ani[r]);
          const float En = ex2(na);
          const float Ez = ex2(accz[r]);
          const float em1 = En - 1.f, ep1 = En + 1.f;
          const float num = __builtin_fmaf(hd[r], ep1, em1 * Ez);
          const float den = ep1 * (1.f + Ez);
          hn[r] = num * rcp_(den);
        }

        *(unsigned long long*)((char*)hnb + p * 4096 + wOff) = pk4(hn);
        #pragma unroll
        for (int r = 0; r < 4; ++r) hd[r] = gmn[r] * hn[r];
        *(unsigned long long*)((char*)hdL + q * 4096 + wOff) = pk4(hd);
      }
    } else {
      if (st >= 1 && st <= NT) {           // L1 for step t' = st-1 (parity q)
        FRAG A[4];
        #pragma unroll
        for (int s = 0; s < 4; ++s)
          A[s].i = *(const i32x4*)((const char*)hnb + q * 4096 + rOff[s]);
        f32x4 aa = z4;
        #pragma unroll
        for (int s = 0; s < 4; ++s) aa = MFMA(A[s].b, wf[s].b, aa);
        #pragma unroll
        for (int r = 0; r < 4; ++r)
          *(unsigned short*)((char*)y1s + q * 4096 + yWo[r]) =
              bfb(fmaxf(aa[r] + b1l, 0.f));
        if (wv >= 12) {
          f32x4 au = z4;
          #pragma unroll
          for (int s = 0; s < 4; ++s) au = MFMA(A[s].b, wf[4 + s].b, au);
          #pragma unroll
          for (int r = 0; r < 4; ++r)
            *(unsigned short*)((char*)u1s + q * 2048 + uWo[r]) =
                bfb(fmaxf(au[r] + bu1l, 0.f));
        }
      }
      if (st >= 2) {                       // L2 for step t'' = st-2 (parity p)
        const int t2 = st - 2;
        if (wv == 8) {
          FRAG Y[4];
          #pragma unroll
          for (int s = 0; s < 4; ++s)
            Y[s].i = *(const i32x4*)((const char*)y1s + p * 4096 + rOff[s]);
          f32x4 ap = z4;
          #pragma unroll
          for (int s = 0; s < 4; ++s) ap = MFMA(Y[s].b, wf[8 + s].b, ap);
          if (lr < 6) {
            #pragma unroll
            for (int r = 0; r < 4; ++r)
              out[((size_t)(b0 + 4 * lg + r) * NT + t2) * 6 + lr] = ap[r] + b2l;
          }
        } else if (wv == 9) {
          FRAG U[2];
          #pragma unroll
          for (int s = 0; s < 2; ++s)
            U[s].i = *(const i32x4*)((const char*)u1s + p * 2048 + rOff64[s]);
          f32x4 aq = z4;
          #pragma unroll
          for (int s = 0; s < 2; ++s) aq = MFMA(U[s].b, wf[12 + s].b, aq);
          if (lr < 6) {
            #pragma unroll
            for (int r = 0; r < 4; ++r) {
              const float xa = aq[r] + bu2l;
              const float sp = fmaxf(xa, 0.f) + 0.6931471805599453f *
                  __builtin_amdgcn_logf(1.f + ex2(-fabsf(xa) * L2E));
              out[(size_t)NB * NT * 6 +
                  ((size_t)(b0 + 4 * lg + r) * NT + t2) * 6 + lr] = sp;
            }
          }
        }
      }
      if (xl && st + 1 < NT) {             // x̂ for t+1 (reads xw[q] -> gin[q])
        const float xv = xw[q][xrow][xch], mt = xw[q][xrow][6 + xch];
        const float dtv = xw[q][xrow][12];
        const bool obs = mt > 0.5f;
        run = obs ? 0.f : run + dtv;
        const float gx = ex2(fminf(run * dxwS + dxbS, 0.f));
        xlast = obs ? xv : xlast;
        const float xh = mt * xv + (1.f - mt) * (gx * xlast + (1.f - gx) * xm_l);
        ((unsigned*)&gin[q][xrow][0])[xch] = pkbf(xh, mt);
      }
      if (sl && st + 2 < NT) {             // stage x[t+2] -> xw[p]; prefetch
        xw[p][rrow][rcc] = xr2;
        xr2 = xbase[(size_t)((st + 3 < NT) ? st + 3 : NT - 1) * 13];
      }
    }
    BAR();
  }
}

extern "C" void kernel_launch(void* const* d_in, const int* in_sizes, int n_in,
                              void* d_out, int out_size, void* d_ws, size_t ws_size,
                              hipStream_t stream) {
  (void)in_sizes; (void)n_in; (void)out_size; (void)d_ws; (void)ws_size;
  const float* p[18];
  for (int i = 0; i < 18; ++i) p[i] = (const float*)d_in[i];
  hipLaunchKernelGGL(grud_fused, dim3(64), dim3(1024), 0, stream,
                     p[0], p[1], p[2], p[3], p[4], p[5], p[6], p[7], p[8], p[9],
                     p[10], p[11], p[12], p[13], p[14], p[15], p[16], p[17],
                     (float*)d_out);
}

// Round 8
// 879.427 us; speedup vs baseline: 2.3157x; 2.3148x over previous
//
#include <hip/hip_runtime.h>

namespace {
constexpr int NB = 1024, NT = 1024, NH = 128;
constexpr float L2E = 1.4426950408889634f;

typedef __bf16 bf16x8 __attribute__((ext_vector_type(8)));
typedef float  f32x4  __attribute__((ext_vector_type(4)));
typedef int    i32x4  __attribute__((ext_vector_type(4)));
union FRAG { i32x4 i; bf16x8 b; };

__device__ __forceinline__ unsigned short bfb(float f) {   // HW RNE f32->bf16
  union { __bf16 h; unsigned short u; } c; c.h = (__bf16)f; return c.u;
}
__device__ __forceinline__ unsigned pkbf(float a, float b) {
  return (unsigned)bfb(a) | ((unsigned)bfb(b) << 16);
}
__device__ __forceinline__ unsigned long long pk4(const f32x4 v) {
  return (unsigned long long)pkbf(v[0], v[1]) |
         ((unsigned long long)pkbf(v[2], v[3]) << 32);
}
__device__ __forceinline__ float ex2(float x) { return __builtin_amdgcn_exp2f(x); }
__device__ __forceinline__ float rcp_(float x) { return __builtin_amdgcn_rcpf(x); }

// 8 consecutive floats -> bf16 fragment (k = 32s + 8lg + j map, verified r0/r1)
__device__ __forceinline__ FRAG pk8(const float* pp, float sc) {
  FRAG f;
  #pragma unroll
  for (int j = 0; j < 4; ++j)
    f.i[j] = (int)pkbf(pp[2 * j] * sc, pp[2 * j + 1] * sc);
  return f;
}
} // namespace

#define MFMA(a, b, c) __builtin_amdgcn_mfma_f32_16x16x32_bf16(a, b, c, 0, 0, 0)
// LDS-only barrier: never drains vmcnt (global h-stream / x-prefetch in flight)
#define BAR() do { \
  asm volatile("s_waitcnt lgkmcnt(0)" ::: "memory"); \
  __builtin_amdgcn_s_barrier(); \
} while (0)

// ---------------------------------------------------------------------------
// Combined kernel, grid = 256 x 512 threads.
//   blocks 0-63  : rnn role — VERBATIM round-4 recurrence (verified 433us/512
//                  steps) for chunk [t0, t0+Tc), writing h tiles to hcur.
//   blocks 64-255: head role — processes chunk [t0p, t0p+Tc) from hprev
//                  (written by the PREVIOUS dispatch), overlapped in time.
// Head role: two independent 4-wave halves per block; each half handles one
// (chain, 2-step) unit per grid-stride iteration. 3 __syncthreads per iter,
// uniform across halves.
// ---------------------------------------------------------------------------
__global__ __launch_bounds__(512, 2)
void grud_combo(const float* __restrict__ x, const float* __restrict__ x_mean,
                const float* __restrict__ dxw, const float* __restrict__ dxb,
                const float* __restrict__ dhw, const float* __restrict__ dhb,
                const float* __restrict__ w_ih, const float* __restrict__ w_hh,
                const float* __restrict__ b_ih, const float* __restrict__ b_hh,
                const float* __restrict__ w1, const float* __restrict__ b1,
                const float* __restrict__ w2, const float* __restrict__ b2,
                const float* __restrict__ wu1, const float* __restrict__ bu1,
                const float* __restrict__ wu2, const float* __restrict__ bu2,
                float* __restrict__ out,
                char* __restrict__ hcur, const char* __restrict__ hprev,
                float* __restrict__ hstate, float* __restrict__ runst,
                float* __restrict__ xlst, int t0, int t0p, int Tc, int niter)
{
  __shared__ __align__(16) char lds[40960];

  const int tid = threadIdx.x;

  if (blockIdx.x < 64) {
    // =================== RNN ROLE (round-4 verified body) ===================
    if (t0 >= NT) return;

    float (*xw)[16][17] = (float(*)[16][17])lds;                    // 2176 B
    unsigned short (*gin)[16][40] = (unsigned short(*)[16][40])(lds + 2176); // 2560 B
    char* hdL = lds + 4736;                                         // 8192 B

    const int lane = tid & 63, wv = tid >> 6;
    const int lr = lane & 15, lg = lane >> 4;
    const int b0 = blockIdx.x * 16;
    const int uidx = wv * 16 + lr;     // weight-row index (A operand)
    const int uu0  = wv * 16 + 4 * lg; // this lane's first owned unit (D rows)

    FRAG bhh[3][4], bgi[3];
    #pragma unroll
    for (int g = 0; g < 3; ++g) {
      const float sc = (g < 2) ? -L2E : 2.f * L2E;
      const int grow = g * 128 + uidx;
      const float* wrow = w_hh + (size_t)grow * NH;
      #pragma unroll
      for (int s = 0; s < 4; ++s) bhh[g][s] = pk8(wrow + 32 * s + 8 * lg, sc);
      FRAG f; f.i = i32x4{0, 0, 0, 0};
      if (lg < 2) {
        unsigned e[8];
        #pragma unroll
        for (int j = 0; j < 8; ++j) {
          const int c = 8 * lg + j; float v = 0.f;
          if (c < 12) {
            const int ch = c >> 1;
            v = ((c & 1) ? w_ih[(size_t)grow * 12 + 6 + ch]
                         : w_ih[(size_t)grow * 12 + ch]) * sc;
          } else if (c == 12) {
            v = ((g < 2) ? (b_ih[grow] + b_hh[grow]) : b_ih[grow]) * sc;
          }
          e[j] = bfb(v);
        }
        f.i[0] = (int)(e[0] | (e[1] << 16)); f.i[1] = (int)(e[2] | (e[3] << 16));
        f.i[2] = (int)(e[4] | (e[5] << 16)); f.i[3] = (int)(e[6] | (e[7] << 16));
      }
      bgi[g] = f;
    }
    f32x4 dhwV, dhbV, bhnV;
    #pragma unroll
    for (int r = 0; r < 4; ++r) {
      dhwV[r] = -L2E * dhw[uu0 + r];
      dhbV[r] = -L2E * dhb[uu0 + r];
      bhnV[r] = b_hh[256 + uu0 + r] * (2.f * L2E);
    }

    // x̂ lanes: waves 0-3, lanes 0..23
    const int  item = wv * 24 + lane;
    const bool xl = (wv < 4) && (lane < 24);
    const int  xrow = item / 6, xch = item - 6 * (item / 6);
    float dxwS = 0.f, dxbS = 0.f, xm_l = 0.f, run = 0.f, xlast = 0.f;
    if (xl) {
      dxwS = -L2E * dxw[xch]; dxbS = -L2E * dxb[xch]; xm_l = x_mean[xch];
      if (t0 > 0) { run = runst[(b0 + xrow) * 6 + xch]; xlast = xlst[(b0 + xrow) * 6 + xch]; }
    }

    // stagers: waves 4-7
    const bool sl = (tid >= 256) && (tid < 464);
    const int sid = tid - 256;
    const int rrow = sid / 13, rcc = sid - 13 * (sid / 13);
    const float* xbase = x + (size_t)(b0 + rrow) * (NT * 13) + rcc;

    f32x4 hn = {0.f, 0.f, 0.f, 0.f};
    if (t0 > 0) hn = *(const f32x4*)&hstate[(size_t)(b0 + lr) * NH + uu0];

    const int wOff = lr * 256 + (((2 * wv + (lg >> 1)) ^ (lr & 7)) << 4) + (lg & 1) * 8;
    int rOff[4];
    #pragma unroll
    for (int s = 0; s < 4; ++s) rOff[s] = lr * 256 + (((4 * s + lg) ^ (lr & 7)) << 4);

    for (int i = tid; i < 2 * 16 * 28; i += 512) {
      const int buf = i / 448, rem = i - 448 * buf;
      const int row = rem / 28, c = 12 + rem - 28 * (rem / 28);
      gin[buf][row][c] = (c == 12) ? (unsigned short)0x3F80 : (unsigned short)0;
    }

    const int cb0 = t0 & 1;
    if (sl) {
      xw[cb0][rrow][rcc]     = xbase[(size_t)t0 * 13];
      const int t1 = (t0 + 1 < NT) ? t0 + 1 : NT - 1;
      xw[cb0 ^ 1][rrow][rcc] = xbase[(size_t)t1 * 13];
    }
    __syncthreads();

    f32x4 hd;
    {
      const float dt0 = xw[cb0][lr][12];
      #pragma unroll
      for (int r = 0; r < 4; ++r)
        hd[r] = ex2(fminf(dt0 * dhwV[r] + dhbV[r], 0.f)) * hn[r];
      *(unsigned long long*)(hdL + cb0 * 4096 + wOff) = pk4(hd);
    }
    if (xl) {
      const float xv = xw[cb0][xrow][xch], mt = xw[cb0][xrow][6 + xch];
      const float dtv = xw[cb0][xrow][12];
      const bool obs = mt > 0.5f;
      run = obs ? 0.f : run + dtv;
      const float gx = ex2(fminf(run * dxwS + dxbS, 0.f));
      xlast = obs ? xv : xlast;
      const float xh = mt * xv + (1.f - mt) * (gx * xlast + (1.f - gx) * xm_l);
      ((unsigned*)&gin[cb0][xrow][0])[xch] = pkbf(xh, mt);
    }
    float xr2 = 0.f;
    if (sl) { const int t2 = (t0 + 2 < NT) ? t0 + 2 : NT - 1; xr2 = xbase[(size_t)t2 * 13]; }
    BAR();

    char* hwp = hcur + (((size_t)blockIdx.x * Tc) << 12) + wv * 32 + lg * 8 + lr * 256;
    const f32x4 z4 = {0.f, 0.f, 0.f, 0.f};
    const int tend = t0 + Tc;

    #pragma unroll 1
    for (int t = t0; t < tend; ++t) {
      const int p = t & 1, q = p ^ 1;

      FRAG ag; ag.i = *(const i32x4*)&gin[p][lr][8 * lg];
      FRAG ah[4];
      #pragma unroll
      for (int s = 0; s < 4; ++s)
        ah[s].i = *(const i32x4*)(hdL + p * 4096 + rOff[s]);
      const float dtn = xw[q][lr][12];

      if (sl) {
        xw[p][rrow][rcc] = xr2;
        xr2 = xbase[(size_t)((t + 3 < NT) ? t + 3 : NT - 1) * 13];
      }

      f32x4 accr = MFMA(bgi[0].b, ag.b, z4);
      f32x4 accz = MFMA(bgi[1].b, ag.b, z4);
      f32x4 ani  = MFMA(bgi[2].b, ag.b, z4);
      f32x4 anh  = z4;
      #pragma unroll
      for (int s = 0; s < 4; ++s) {
        accr = MFMA(bhh[0][s].b, ah[s].b, accr);
        accz = MFMA(bhh[1][s].b, ah[s].b, accz);
        anh  = MFMA(bhh[2][s].b, ah[s].b, anh);
      }

      // 5-trans tail: hn = [(En-1)Ez + hd(En+1)] / [(En+1)(1+Ez)]
      f32x4 hbv = anh + bhnV;
      #pragma unroll
      for (int r = 0; r < 4; ++r) {
        const float Er = ex2(accr[r]);
        const float rr = rcp_(1.f + Er);
        const float na = __builtin_fmaf(rr, hbv[r], ani[r]);
        const float En = ex2(na);
        const float Ez = ex2(accz[r]);
        const float em1 = En - 1.f, ep1 = En + 1.f;
        const float num = __builtin_fmaf(hd[r], ep1, em1 * Ez);
        const float den = ep1 * (1.f + Ez);
        hn[r] = num * rcp_(den);
      }

      *(unsigned long long*)hwp = pk4(hn);
      hwp += 4096;

      #pragma unroll
      for (int r = 0; r < 4; ++r)
        hd[r] = ex2(fminf(dtn * dhwV[r] + dhbV[r], 0.f)) * hn[r];
      *(unsigned long long*)(hdL + q * 4096 + wOff) = pk4(hd);

      if (xl && t + 1 < tend) {
        const float xv = xw[q][xrow][xch], mt = xw[q][xrow][6 + xch];
        const float dtv = xw[q][xrow][12];
        const bool obs = mt > 0.5f;
        run = obs ? 0.f : run + dtv;
        const float gx = ex2(fminf(run * dxwS + dxbS, 0.f));
        xlast = obs ? xv : xlast;
        const float xh = mt * xv + (1.f - mt) * (gx * xlast + (1.f - gx) * xm_l);
        ((unsigned*)&gin[q][xrow][0])[xch] = pkbf(xh, mt);
      }
      BAR();
    }

    *(f32x4*)&hstate[(size_t)(b0 + lr) * NH + uu0] = hn;
    if (xl) { runst[(b0 + xrow) * 6 + xch] = run; xlst[(b0 + xrow) * 6 + xch] = xlast; }

  } else {
    // ============================ HEAD ROLE ============================
    if (t0p < 0) return;

    const int hb = blockIdx.x - 64;              // 0..191
    const int tid2 = tid & 255, half = tid >> 8; // two 4-wave halves
    const int lane2 = tid2 & 63, w4 = tid2 >> 6;
    const int lr = lane2 & 15, lg = lane2 >> 4;
    char* ldsH = lds + half * 20480;             // hs@0(8K), y1@8192(8K), u1@16384(4K)

    FRAG bw1a[4], bw1b[4], bq1[4], bw2[4], bq2[2];
    #pragma unroll
    for (int s = 0; s < 4; ++s) {
      bw1a[s] = pk8(w1 + (size_t)((2 * w4) * 16 + lr) * 128 + 32 * s + 8 * lg, 1.f);
      bw1b[s] = pk8(w1 + (size_t)((2 * w4 + 1) * 16 + lr) * 128 + 32 * s + 8 * lg, 1.f);
      bq1[s]  = pk8(wu1 + (size_t)(w4 * 16 + lr) * 128 + 32 * s + 8 * lg, 1.f);
      if (lr < 6) bw2[s] = pk8(w2 + (size_t)lr * 128 + 32 * s + 8 * lg, 1.f);
      else        bw2[s].i = i32x4{0, 0, 0, 0};
      if (s < 2) {
        if (lr < 6) bq2[s] = pk8(wu2 + (size_t)lr * 64 + 32 * s + 8 * lg, 1.f);
        else        bq2[s].i = i32x4{0, 0, 0, 0};
      }
    }
    const float b1a = b1[(2 * w4) * 16 + lr], b1b = b1[(2 * w4 + 1) * 16 + lr];
    const float bu1l = bu1[w4 * 16 + lr];
    const float b2l = (lr < 6) ? b2[lr] : 0.f, bu2l = (lr < 6) ? bu2[lr] : 0.f;
    const f32x4 z4 = {0.f, 0.f, 0.f, 0.f};

    const int tc2 = Tc >> 1, total = 64 * tc2;
    const int cy0 = (2 * w4) * 16 + lr, cy1 = (2 * w4 + 1) * 16 + lr;
    const int cu = w4 * 16 + lr;

    #pragma unroll 1
    for (int it = 0; it < niter; ++it) {
      const int hu = it * 384 + hb * 2 + half;
      const bool valid = hu < total;
      int chain = 0, tp = 0;
      if (valid) { chain = hu / tc2; tp = hu - chain * tc2; }

      if (valid) {   // stage 2 h tiles, cell-swizzled
        const char* src = hprev + (((size_t)chain * Tc + tp * 2) << 12);
        const int o = tid2 * 16, row = o >> 8, cell = (o >> 4) & 15;
        #pragma unroll
        for (int k2 = 0; k2 < 2; ++k2) {
          uint4 v = *(const uint4*)(src + k2 * 4096 + o);
          *(uint4*)(ldsH + k2 * 4096 + row * 256 + ((cell ^ (row & 7)) << 4)) = v;
        }
      }
      __syncthreads();

      if (valid) {   // layer 1 over 2 t-tiles
        #pragma unroll
        for (int k = 0; k < 2; ++k) {
          FRAG A[4];
          #pragma unroll
          for (int s = 0; s < 4; ++s)
            A[s].i = *(const i32x4*)(ldsH + k * 4096 + lr * 256 +
                                     (((4 * s + lg) ^ (lr & 7)) << 4));
          f32x4 aa = z4, ab = z4, au = z4;
          #pragma unroll
          for (int s = 0; s < 4; ++s) {
            aa = MFMA(A[s].b, bw1a[s].b, aa);
            ab = MFMA(A[s].b, bw1b[s].b, ab);
            au = MFMA(A[s].b, bq1[s].b, au);
          }
          #pragma unroll
          for (int r = 0; r < 4; ++r) {
            const int m = k * 16 + 4 * lg + r;
            *(unsigned short*)(ldsH + 8192 + m * 256 + (((cy0 >> 3) ^ (m & 7)) << 4) +
                               (cy0 & 7) * 2) = bfb(fmaxf(aa[r] + b1a, 0.f));
            *(unsigned short*)(ldsH + 8192 + m * 256 + (((cy1 >> 3) ^ (m & 7)) << 4) +
                               (cy1 & 7) * 2) = bfb(fmaxf(ab[r] + b1b, 0.f));
            *(unsigned short*)(ldsH + 16384 + m * 128 + (((cu >> 3) ^ (m & 7)) << 4) +
                               (cu & 7) * 2) = bfb(fmaxf(au[r] + bu1l, 0.f));
          }
        }
      }
      __syncthreads();

      if (valid && w4 < 2) {   // layer 2: wave w4 finishes t-tile w4
        const int mrow = w4 * 16 + lr;
        FRAG Y[4], U[2];
        #pragma unroll
        for (int s = 0; s < 4; ++s)
          Y[s].i = *(const i32x4*)(ldsH + 8192 + mrow * 256 +
                                   (((4 * s + lg) ^ (lr & 7)) << 4));
        #pragma unroll
        for (int s = 0; s < 2; ++s)
          U[s].i = *(const i32x4*)(ldsH + 16384 + mrow * 128 +
                                   (((4 * s + lg) ^ (lr & 7)) << 4));
        f32x4 ap = z4, aq = z4;
        #pragma unroll
        for (int s = 0; s < 4; ++s) ap = MFMA(Y[s].b, bw2[s].b, ap);
        #pragma unroll
        for (int s = 0; s < 2; ++s) aq = MFMA(U[s].b, bq2[s].b, aq);

        if (lr < 6) {
          const int t = t0p + tp * 2 + w4;
          #pragma unroll
          for (int r = 0; r < 4; ++r) {
            const int b = chain * 16 + 4 * lg + r;
            const size_t o = ((size_t)b * NT + t) * 6 + lr;
            out[o] = ap[r] + b2l;
            const float xa = aq[r] + bu2l;
            const float sp = fmaxf(xa, 0.f) + 0.6931471805599453f *
                __builtin_amdgcn_logf(1.f + ex2(-fabsf(xa) * L2E));
            out[(size_t)NB * NT * 6 + o] = sp;
          }
        }
      }
      __syncthreads();
    }
  }
}

extern "C" void kernel_launch(void* const* d_in, const int* in_sizes, int n_in,
                              void* d_out, int out_size, void* d_ws, size_t ws_size,
                              hipStream_t stream) {
  (void)in_sizes; (void)n_in; (void)out_size;
  const float* p[18];
  for (int i = 0; i < 18; ++i) p[i] = (const float*)d_in[i];

  const size_t STATE = (size_t)1024 * 128 * 4 + 2 * (size_t)1024 * 6 * 4;
  int Tc = 256;   // capped: small head-tail dispatch, hws dbuf fits ws
  while (Tc > 16 && (2 * ((size_t)Tc << 18) + STATE) > ws_size) Tc >>= 1;

  char* h0 = (char*)d_ws;
  char* h1 = h0 + ((size_t)Tc << 18);
  float* hstate = (float*)(h1 + ((size_t)Tc << 18));
  float* runst = hstate + 1024 * 128;
  float* xlst = runst + 1024 * 6;

  const int nch = NT / Tc;
  const int niter = (64 * (Tc / 2) + 383) / 384;

  for (int k = 0; k <= nch; ++k) {
    char* hcur = (k & 1) ? h1 : h0;
    const char* hprev = (k & 1) ? h0 : h1;
    hipLaunchKernelGGL(grud_combo, dim3(256), dim3(512), 0, stream,
                       p[0], p[1], p[2], p[3], p[4], p[5], p[6], p[7], p[8], p[9],
                       p[10], p[11], p[12], p[13], p[14], p[15], p[16], p[17],
                       (float*)d_out, hcur, hprev, hstate, runst, xlst,
                       k * Tc, (k - 1) * Tc, Tc, niter);
  }
}